// Round 2
// baseline (926.020 us; speedup 1.0000x reference)
//
#include <hip/hip_runtime.h>
#include <hip/hip_bf16.h>

#define T_LEN 512
#define BATCH 8
#define HID 128

// ---------------------------------------------------------------------------
// Conv block: y[b,co,t] = lrelu( bias[co] + sum_{ci,k} w[co,ci,k]*x_pad[b,ci,t+k-1] )
// reflect pad 1. Generic over (Cin, Cout). Block: 128 threads = 64 t-positions
// x 2 co-subgroups of 8. Grid: (T/64, ceil(Cout/16), B).
// ---------------------------------------------------------------------------
__global__ __launch_bounds__(128) void conv_block_kernel(
    const float* __restrict__ x, const float* __restrict__ w,
    const float* __restrict__ bias, float* __restrict__ y,
    int Cin, int Cout)
{
    __shared__ __align__(16) float xs[128 * 66];  // max Cin=128, 64+2 with halo
    const int b   = blockIdx.z;
    const int cog = blockIdx.y * 16;
    const int t0  = blockIdx.x * 64;
    const int tid = threadIdx.x;

    const float* xb = x + (size_t)b * Cin * T_LEN;
    for (int idx = tid; idx < Cin * 66; idx += 128) {
        int ci = idx / 66;
        int tt = idx - ci * 66;
        int g  = t0 + tt - 1;
        g = (g < 0) ? 1 : (g >= T_LEN ? T_LEN - 2 : g);
        xs[ci * 66 + tt] = xb[ci * T_LEN + g];
    }
    __syncthreads();

    const int tl    = tid & 63;
    const int cosub = (tid >> 6) * 8;   // 0 or 8

    float acc[8];
#pragma unroll
    for (int u = 0; u < 8; ++u) acc[u] = 0.0f;

    for (int ci = 0; ci < Cin; ++ci) {
        float xm = xs[ci * 66 + tl];
        float x0 = xs[ci * 66 + tl + 1];
        float xp = xs[ci * 66 + tl + 2];
#pragma unroll
        for (int u = 0; u < 8; ++u) {
            int co  = cog + cosub + u;
            int cor = co < Cout ? co : (Cout - 1);   // clamp for safe read
            const float* wp = w + ((size_t)cor * Cin + ci) * 3;
            acc[u] = fmaf(wp[0], xm, acc[u]);
            acc[u] = fmaf(wp[1], x0, acc[u]);
            acc[u] = fmaf(wp[2], xp, acc[u]);
        }
    }
#pragma unroll
    for (int u = 0; u < 8; ++u) {
        int co = cog + cosub + u;
        if (co < Cout) {
            float v = acc[u] + bias[co];
            v = (v >= 0.0f) ? v : 0.2f * v;
            y[((size_t)b * Cout + co) * T_LEN + t0 + tl] = v;
        }
    }
}

// ---------------------------------------------------------------------------
// dist[b,m,n] = sqrt( sum_h (k[b,h,m] - q[b,h,n])^2 )   (raw, un-normalized)
// Also block-reduces min/max and atomically folds into mm[0]=min, mm[1]=max
// (nonneg floats -> uint bit compare is order-preserving).
// Block: 256 threads -> 32x32 tile; grid (16,16,8).
// ---------------------------------------------------------------------------
__global__ __launch_bounds__(256) void dist_kernel(
    const float* __restrict__ q, const float* __restrict__ k,
    float* __restrict__ dist, unsigned* __restrict__ mm)
{
    __shared__ __align__(16) float ks[HID * 32];
    __shared__ __align__(16) float qs[HID * 32];
    __shared__ float red[8];

    const int b  = blockIdx.z;
    const int m0 = blockIdx.y * 32;
    const int n0 = blockIdx.x * 32;
    const int tid = threadIdx.x;

    const float* qb = q + (size_t)b * HID * T_LEN;
    const float* kb = k + (size_t)b * HID * T_LEN;

    for (int idx = tid; idx < HID * 32; idx += 256) {
        int h = idx >> 5, c = idx & 31;
        ks[idx] = kb[h * T_LEN + m0 + c];
        qs[idx] = qb[h * T_LEN + n0 + c];
    }
    __syncthreads();

    const int nn = tid & 31;
    const int mq = (tid >> 5) * 4;

    float a0 = 0.f, a1 = 0.f, a2 = 0.f, a3 = 0.f;
    for (int h = 0; h < HID; ++h) {
        float qv = qs[h * 32 + nn];
        const float4 kv = *reinterpret_cast<const float4*>(&ks[h * 32 + mq]);
        float d0 = kv.x - qv, d1 = kv.y - qv, d2 = kv.z - qv, d3 = kv.w - qv;
        a0 = fmaf(d0, d0, a0);
        a1 = fmaf(d1, d1, a1);
        a2 = fmaf(d2, d2, a2);
        a3 = fmaf(d3, d3, a3);
    }
    float v0 = sqrtf(a0), v1 = sqrtf(a1), v2 = sqrtf(a2), v3 = sqrtf(a3);

    float* drow = dist + ((size_t)b * T_LEN + m0 + mq) * T_LEN + n0 + nn;
    drow[0 * T_LEN] = v0;
    drow[1 * T_LEN] = v1;
    drow[2 * T_LEN] = v2;
    drow[3 * T_LEN] = v3;

    float mnv = fminf(fminf(v0, v1), fminf(v2, v3));
    float mxv = fmaxf(fmaxf(v0, v1), fmaxf(v2, v3));
#pragma unroll
    for (int off = 32; off >= 1; off >>= 1) {
        mnv = fminf(mnv, __shfl_xor(mnv, off, 64));
        mxv = fmaxf(mxv, __shfl_xor(mxv, off, 64));
    }
    int wid = tid >> 6;
    if ((tid & 63) == 0) { red[wid * 2] = mnv; red[wid * 2 + 1] = mxv; }
    __syncthreads();
    if (tid == 0) {
        float mn = fminf(fminf(red[0], red[2]), fminf(red[4], red[6]));
        float mx = fmaxf(fmaxf(red[1], red[3]), fmaxf(red[5], red[7]));
        atomicMin(&mm[0], __float_as_uint(mn));
        atomicMax(&mm[1], __float_as_uint(mx));
    }
}

// ---------------------------------------------------------------------------
// In-place normalize: d = (d - mn) / (mx - mn)
// ---------------------------------------------------------------------------
__global__ void normalize_kernel(float* __restrict__ dd,
                                 const unsigned* __restrict__ mm, int n)
{
    float mn  = __uint_as_float(mm[0]);
    float mx  = __uint_as_float(mm[1]);
    float rng = mx - mn;
    for (int i = blockIdx.x * blockDim.x + threadIdx.x; i < n;
         i += gridDim.x * blockDim.x)
        dd[i] = (dd[i] - mn) / rng;
}

// ---------------------------------------------------------------------------
// DTW: anti-diagonal wavefront DP (bit-exact op order vs reference) +
// in-LDS 2-bit packed choice matrix + serial backtrack.
// One block per batch, 512 threads (thread i owns row i).
// Diagonal s: cell (i, s-i). deps: prev[i] (left), prev[i-1] (up),
// prevprev[i-1] (diag). Buffers rotate mod 3.
// dist tile staged 16 diagonals at a time with coalesced row reads into a
// skewed [512][17] LDS buffer (odd stride -> conflict-free column access).
// ---------------------------------------------------------------------------
__global__ __launch_bounds__(512) void dtw_kernel(
    const float* __restrict__ dist, const int* __restrict__ rlen,
    float* __restrict__ path)
{
    __shared__ float dstage[512 * 17];     // 34816 B
    __shared__ unsigned cho[512 * 32];     // 65536 B (2-bit x 512x512)
    __shared__ float costbuf[3 * 512];     // 6144 B

    const int b   = blockIdx.x;
    const int tid = threadIdx.x;
    const float* dmat = dist + (size_t)b * T_LEN * T_LEN;

    unsigned wpack = 0;

    for (int s0 = 0; s0 < 1023; s0 += 16) {
        __syncthreads();   // all reads of previous dstage group done
#pragma unroll
        for (int p = 0; p < 16; ++p) {
            int r  = p * 32 + (tid >> 4);
            int jw = tid & 15;
            int j  = s0 - r + jw;
            float v = 0.0f;
            if (j >= 0 && j < T_LEN) v = dmat[r * T_LEN + j];
            dstage[r * 17 + jw] = v;
        }
        __syncthreads();

        int send = (s0 + 16 < 1023) ? s0 + 16 : 1023;
        for (int s = s0; s < send; ++s) {
            int i = tid;
            int j = s - i;
            if (j >= 0 && j < T_LEN) {
                float dv = dstage[i * 17 + (s - s0)];
                float cur;
                int choice;
                if (i == 0) {
                    if (j == 0) { cur = dv; choice = 1; }  // choice unused at (0,0)
                    else {
                        cur = costbuf[((s + 2) % 3) * 512 + 0] + dv;  // cumsum
                        choice = 1;
                    }
                } else if (j == 0) {
                    cur = costbuf[((s + 2) % 3) * 512 + (i - 1)] + dv;  // from up
                    choice = 2;
                } else {
                    float pd = costbuf[((s + 1) % 3) * 512 + (i - 1)];  // diag
                    float pu = costbuf[((s + 2) % 3) * 512 + (i - 1)];  // up
                    float lf = costbuf[((s + 2) % 3) * 512 + i];        // left
                    float m  = fminf(fminf(pd, lf), pu);
                    choice = (pd == m) ? 0 : ((lf == m) ? 1 : 2);
                    cur = m + dv;
                }
                costbuf[(s % 3) * 512 + i] = cur;
                wpack |= (unsigned)choice << ((j & 15) * 2);
                if ((j & 15) == 15) { cho[i * 32 + (j >> 4)] = wpack; wpack = 0; }
            }
            __syncthreads();
        }
    }

    // Backtrack (serial, LDS-resident choices). Matches reference semantics:
    // start at (L-1,L-1), walk until (0,0), mark every visited cell 1.0.
    if (tid == 0) {
        int L  = rlen[b];
        int ix = L - 1, iy = L - 1;
        float* pout = path + (size_t)b * T_LEN * T_LEN;
        pout[ix * T_LEN + iy] = 1.0f;
        int cidx = -1;
        unsigned wv = 0;
        while (ix > 0 || iy > 0) {
            int widx = ix * 32 + (iy >> 4);
            if (widx != cidx) { wv = cho[widx]; cidx = widx; }
            int c = (wv >> ((iy & 15) * 2)) & 3;
            if (c == 0)      { --ix; --iy; }
            else if (c == 1) { --iy; }
            else             { --ix; }
            pout[ix * T_LEN + iy] = 1.0f;
        }
    }
}

// ---------------------------------------------------------------------------
extern "C" void kernel_launch(void* const* d_in, const int* in_sizes, int n_in,
                              void* d_out, int out_size, void* d_ws, size_t ws_size,
                              hipStream_t stream)
{
    (void)in_sizes; (void)n_in; (void)out_size; (void)ws_size;

    const float* vec   = (const float*)d_in[0];   // [8,126,512]
    const float* music = (const float*)d_in[1];   // [8,80,512]
    const int*   rlen  = (const int*)  d_in[2];   // [8]
    const float* qw1 = (const float*)d_in[3];  const float* qb1 = (const float*)d_in[4];
    const float* qw2 = (const float*)d_in[5];  const float* qb2 = (const float*)d_in[6];
    const float* qw3 = (const float*)d_in[7];  const float* qb3 = (const float*)d_in[8];
    const float* kw1 = (const float*)d_in[9];  const float* kb1 = (const float*)d_in[10];
    const float* kw2 = (const float*)d_in[11]; const float* kb2 = (const float*)d_in[12];
    const float* kw3 = (const float*)d_in[13]; const float* kb3 = (const float*)d_in[14];

    float* out = (float*)d_out;
    const size_t mat_elems  = (size_t)BATCH * T_LEN * T_LEN;   // 2,097,152
    float* path_out = out;                 // [8,512,512]
    float* dist_out = out + mat_elems;     // [8,512,512]

    char* ws = (char*)d_ws;
    const size_t bufB = (size_t)BATCH * HID * T_LEN * sizeof(float);  // 2 MiB
    float* qA = (float*)(ws + 0 * bufB);
    float* qB = (float*)(ws + 1 * bufB);
    float* kA = (float*)(ws + 2 * bufB);
    float* kB = (float*)(ws + 3 * bufB);
    unsigned* mm = (unsigned*)(ws + 4 * bufB);

    // zero path01 region; init min/max atomics
    hipMemsetAsync(path_out, 0, mat_elems * sizeof(float), stream);
    hipMemsetAsync(mm, 0xFF, 4, stream);        // min init = 0xFFFFFFFF (uint max)
    hipMemsetAsync(mm + 1, 0x00, 4, stream);    // max init = 0

    dim3 cb(128);
    // motion (q) encoder: 126 -> 126 -> 128 -> 128
    conv_block_kernel<<<dim3(8, 8, 8), cb, 0, stream>>>(vec, qw1, qb1, qA, 126, 126);
    conv_block_kernel<<<dim3(8, 8, 8), cb, 0, stream>>>(qA,  qw2, qb2, qB, 126, 128);
    conv_block_kernel<<<dim3(8, 8, 8), cb, 0, stream>>>(qB,  qw3, qb3, qA, 128, 128);
    // music (k) encoder: 80 -> 80 -> 128 -> 128
    conv_block_kernel<<<dim3(8, 5, 8), cb, 0, stream>>>(music, kw1, kb1, kA, 80, 80);
    conv_block_kernel<<<dim3(8, 8, 8), cb, 0, stream>>>(kA,   kw2, kb2, kB, 80, 128);
    conv_block_kernel<<<dim3(8, 8, 8), cb, 0, stream>>>(kB,   kw3, kb3, kA, 128, 128);

    // raw dist + global min/max
    dist_kernel<<<dim3(16, 16, 8), dim3(256), 0, stream>>>(qA, kA, dist_out, mm);

    // normalize in place
    normalize_kernel<<<dim3(2048), dim3(256), 0, stream>>>(dist_out, mm, (int)mat_elems);

    // DTW DP + backtrack
    dtw_kernel<<<dim3(BATCH), dim3(512), 0, stream>>>(dist_out, rlen, path_out);
}

// Round 3
// 580.634 us; speedup vs baseline: 1.5948x; 1.5948x over previous
//
#include <hip/hip_runtime.h>
#include <hip/hip_bf16.h>

#define T_LEN 512
#define BATCH 8
#define HID 128

// ---------------------------------------------------------------------------
// Conv block: y[b,co,t] = lrelu( bias[co] + sum_{ci,k} w[co,ci,k]*x_pad[b,ci,t+k-1] )
// reflect pad 1. Block: 512 threads = 8 waves; each wave owns a uniform co-pair
// (weights stream through the SCALAR pipe via readfirstlane-uniform indexing),
// 64 t-positions per lane. x tile staged once in LDS [Cin][66] (conflict-free).
// Grid: (T/64, Cout/16, B). fma order identical to the round-2 passing kernel.
// ---------------------------------------------------------------------------
__global__ __launch_bounds__(512) void conv_block_kernel(
    const float* __restrict__ x, const float* __restrict__ w,
    const float* __restrict__ bias, float* __restrict__ y,
    int Cin, int Cout)
{
    __shared__ float xs[128 * 66];
    const int b   = blockIdx.z;
    const int t0  = blockIdx.x * 64;
    const int tid = threadIdx.x;
    const int tl  = tid & 63;

    const float* xb = x + (size_t)b * Cin * T_LEN;
    for (int idx = tid; idx < Cin * 66; idx += 512) {
        int ci = idx / 66;
        int tt = idx - ci * 66;
        int g  = t0 + tt - 1;
        g = (g < 0) ? 1 : (g >= T_LEN ? T_LEN - 2 : g);
        xs[idx] = xb[ci * T_LEN + g];
    }
    __syncthreads();

    const int wave = __builtin_amdgcn_readfirstlane(tid >> 6);
    const int co0  = blockIdx.y * 16 + 2 * wave;   // Cout is even (80/126/128)
    if (co0 < Cout) {
        const float* __restrict__ wq0 = w + (size_t)co0 * Cin * 3;
        const float* __restrict__ wq1 = wq0 + Cin * 3;
        float acc0 = 0.0f, acc1 = 0.0f;
#pragma unroll 4
        for (int ci = 0; ci < Cin; ++ci) {
            float xm = xs[ci * 66 + tl];
            float x0 = xs[ci * 66 + tl + 1];
            float xp = xs[ci * 66 + tl + 2];
            float a00 = wq0[ci * 3 + 0], a01 = wq0[ci * 3 + 1], a02 = wq0[ci * 3 + 2];
            float a10 = wq1[ci * 3 + 0], a11 = wq1[ci * 3 + 1], a12 = wq1[ci * 3 + 2];
            acc0 = fmaf(a00, xm, acc0);
            acc0 = fmaf(a01, x0, acc0);
            acc0 = fmaf(a02, xp, acc0);
            acc1 = fmaf(a10, xm, acc1);
            acc1 = fmaf(a11, x0, acc1);
            acc1 = fmaf(a12, xp, acc1);
        }
        float v0 = acc0 + bias[co0];
        float v1 = acc1 + bias[co0 + 1];
        v0 = (v0 >= 0.0f) ? v0 : 0.2f * v0;
        v1 = (v1 >= 0.0f) ? v1 : 0.2f * v1;
        y[((size_t)b * Cout + co0) * T_LEN + t0 + tl]     = v0;
        y[((size_t)b * Cout + co0 + 1) * T_LEN + t0 + tl] = v1;
    }
}

// ---------------------------------------------------------------------------
// dist[b,m,n] = sqrt( sum_h (k[b,h,m] - q[b,h,n])^2 )  raw; fold global min/max
// into mm (nonneg float -> uint bit-order trick). Unchanged from passing round.
// ---------------------------------------------------------------------------
__global__ __launch_bounds__(256) void dist_kernel(
    const float* __restrict__ q, const float* __restrict__ k,
    float* __restrict__ dist, unsigned* __restrict__ mm)
{
    __shared__ __align__(16) float ks[HID * 32];
    __shared__ __align__(16) float qs[HID * 32];
    __shared__ float red[8];

    const int b  = blockIdx.z;
    const int m0 = blockIdx.y * 32;
    const int n0 = blockIdx.x * 32;
    const int tid = threadIdx.x;

    const float* qb = q + (size_t)b * HID * T_LEN;
    const float* kb = k + (size_t)b * HID * T_LEN;

    for (int idx = tid; idx < HID * 32; idx += 256) {
        int h = idx >> 5, c = idx & 31;
        ks[idx] = kb[h * T_LEN + m0 + c];
        qs[idx] = qb[h * T_LEN + n0 + c];
    }
    __syncthreads();

    const int nn = tid & 31;
    const int mq = (tid >> 5) * 4;

    float a0 = 0.f, a1 = 0.f, a2 = 0.f, a3 = 0.f;
    for (int h = 0; h < HID; ++h) {
        float qv = qs[h * 32 + nn];
        const float4 kv = *reinterpret_cast<const float4*>(&ks[h * 32 + mq]);
        float d0 = kv.x - qv, d1 = kv.y - qv, d2 = kv.z - qv, d3 = kv.w - qv;
        a0 = fmaf(d0, d0, a0);
        a1 = fmaf(d1, d1, a1);
        a2 = fmaf(d2, d2, a2);
        a3 = fmaf(d3, d3, a3);
    }
    float v0 = sqrtf(a0), v1 = sqrtf(a1), v2 = sqrtf(a2), v3 = sqrtf(a3);

    float* drow = dist + ((size_t)b * T_LEN + m0 + mq) * T_LEN + n0 + nn;
    drow[0 * T_LEN] = v0;
    drow[1 * T_LEN] = v1;
    drow[2 * T_LEN] = v2;
    drow[3 * T_LEN] = v3;

    float mnv = fminf(fminf(v0, v1), fminf(v2, v3));
    float mxv = fmaxf(fmaxf(v0, v1), fmaxf(v2, v3));
#pragma unroll
    for (int off = 32; off >= 1; off >>= 1) {
        mnv = fminf(mnv, __shfl_xor(mnv, off, 64));
        mxv = fmaxf(mxv, __shfl_xor(mxv, off, 64));
    }
    int wid = tid >> 6;
    if ((tid & 63) == 0) { red[wid * 2] = mnv; red[wid * 2 + 1] = mxv; }
    __syncthreads();
    if (tid == 0) {
        float mn = fminf(fminf(red[0], red[2]), fminf(red[4], red[6]));
        float mx = fmaxf(fmaxf(red[1], red[3]), fmaxf(red[5], red[7]));
        atomicMin(&mm[0], __float_as_uint(mn));
        atomicMax(&mm[1], __float_as_uint(mx));
    }
}

// ---------------------------------------------------------------------------
// Fused normalize + transpose: v = (raw - mn)/rng written in-place to dist
// (output) and to distT[n][m] (workspace) for the DTW kernel's coalesced
// column access. Same IEEE division for both -> bit-identical values.
// ---------------------------------------------------------------------------
__global__ __launch_bounds__(256) void norm_transpose_kernel(
    float* __restrict__ dist, float* __restrict__ distT,
    const unsigned* __restrict__ mm)
{
    __shared__ float tile[32][33];
    const float mn  = __uint_as_float(mm[0]);
    const float rng = __uint_as_float(mm[1]) - mn;
    const int b  = blockIdx.z;
    const int m0 = blockIdx.y * 32;
    const int n0 = blockIdx.x * 32;
    const int tx = threadIdx.x & 31;
    const int ty = threadIdx.x >> 5;     // 0..7

    float* D  = dist  + (size_t)b * T_LEN * T_LEN;
    float* DT = distT + (size_t)b * T_LEN * T_LEN;
#pragma unroll
    for (int r = 0; r < 4; ++r) {
        int row = m0 + ty + r * 8;
        float v = (D[row * T_LEN + n0 + tx] - mn) / rng;
        D[row * T_LEN + n0 + tx] = v;
        tile[ty + r * 8][tx] = v;
    }
    __syncthreads();
#pragma unroll
    for (int r = 0; r < 4; ++r) {
        int nrow = n0 + ty + r * 8;
        DT[nrow * T_LEN + m0 + tx] = tile[tx][ty + r * 8];
    }
}

// ---------------------------------------------------------------------------
// DTW: single-wave register-resident skewed DP. One block of 64 threads per
// batch. Lane p owns rows 8p..8p+7; at step t computes column j = t-p.
// Cross-lane boundary costs via __shfl_up (no barriers). Per-cell float op
// sequence identical to the verified round-2 kernel (min(min(pd,lf),pu)+d,
// tie-break diag->left->up). Choices packed 2-bit into LDS tiled as
// [r>>2][j>>4][r&3] u32 so backtrack fetches a 4x16 tile per b128 read.
// ---------------------------------------------------------------------------
__device__ __forceinline__ float4 ld4c(const float* base, int j, int r) {
    int jc = ((unsigned)j < 512u) ? j : 0;
    return *reinterpret_cast<const float4*>(base + (size_t)jc * T_LEN + r);
}

#define DTW_STEP(T, DA, DB) do {                                              \
    int j = (T) - p;                                                          \
    float u_top = __shfl_up(L[7], 1, 64);                                     \
    float d_top = __shfl_up(prevL7, 1, 64);                                   \
    prevL7 = L[7];                                                            \
    if ((unsigned)j < 512u) {                                                 \
        float dvs[8] = {DA.x, DA.y, DA.z, DA.w, DB.x, DB.y, DB.z, DB.w};      \
        int sh = (j & 15) * 2;                                                \
        float cur, oldL, prevrow;                                             \
        unsigned ch;                                                          \
        if (p == 0) {                                                         \
            cur = (j == 0) ? dvs[0] : (L[0] + dvs[0]); ch = 1u;               \
        } else if (j == 0) {                                                  \
            cur = u_top + dvs[0]; ch = 2u;                                    \
        } else {                                                              \
            float pd = d_top, lf = L[0], pu = u_top;                          \
            float m = fminf(fminf(pd, lf), pu);                               \
            ch = (pd == m) ? 0u : ((lf == m) ? 1u : 2u);                      \
            cur = m + dvs[0];                                                 \
        }                                                                     \
        oldL = L[0]; L[0] = cur; prevrow = cur; pk[0] |= ch << sh;            \
        _Pragma("unroll")                                                     \
        for (int u = 1; u < 8; ++u) {                                         \
            if (j == 0) { cur = prevrow + dvs[u]; ch = 2u; }                  \
            else {                                                            \
                float pd = oldL, lf = L[u], pu = prevrow;                     \
                float m = fminf(fminf(pd, lf), pu);                           \
                ch = (pd == m) ? 0u : ((lf == m) ? 1u : 2u);                  \
                cur = m + dvs[u];                                             \
            }                                                                 \
            oldL = L[u]; L[u] = cur; prevrow = cur; pk[u] |= ch << sh;        \
        }                                                                     \
        if ((j & 15) == 15) {                                                 \
            int w4 = (j >> 4) * 4;                                            \
            *reinterpret_cast<uint4*>(&cho[p * 256 + w4]) =                   \
                make_uint4(pk[0], pk[1], pk[2], pk[3]);                       \
            *reinterpret_cast<uint4*>(&cho[p * 256 + 128 + w4]) =             \
                make_uint4(pk[4], pk[5], pk[6], pk[7]);                       \
            pk[0] = pk[1] = pk[2] = pk[3] = 0u;                               \
            pk[4] = pk[5] = pk[6] = pk[7] = 0u;                               \
        }                                                                     \
    }                                                                         \
} while (0)

__global__ __launch_bounds__(64) void dtw_wave_kernel(
    const float* __restrict__ distT, const int* __restrict__ rlen,
    float* __restrict__ path)
{
    __shared__ unsigned cho[512 * 32];   // 64 KiB, tiled 4-row x 16-col per uint4

    const int b  = blockIdx.x;
    const int p  = threadIdx.x;          // lane, owns rows 8p..8p+7
    const int r0 = p * 8;
    const float* dT = distT + (size_t)b * T_LEN * T_LEN;

    float L[8];
    float prevL7 = 1e30f;
#pragma unroll
    for (int u = 0; u < 8; ++u) L[u] = 1e30f;
    unsigned pk[8] = {0u, 0u, 0u, 0u, 0u, 0u, 0u, 0u};

    float4 Aa = ld4c(dT, 0 - p, r0), Ab = ld4c(dT, 0 - p, r0 + 4);
    float4 Ba = ld4c(dT, 1 - p, r0), Bb = ld4c(dT, 1 - p, r0 + 4);

    for (int t = 0; t < 576; t += 2) {
        float4 Ca = ld4c(dT, t + 2 - p, r0), Cb = ld4c(dT, t + 2 - p, r0 + 4);
        DTW_STEP(t, Aa, Ab);
        float4 Da = ld4c(dT, t + 3 - p, r0), Db = ld4c(dT, t + 3 - p, r0 + 4);
        DTW_STEP(t + 1, Ba, Bb);
        Aa = Ca; Ab = Cb; Ba = Da; Bb = Db;
    }

    __syncthreads();   // make all lanes' cho writes visible to lane 0

    if (p == 0) {
        int Lr = rlen[b];
        int ix = Lr - 1, iy = Lr - 1;
        float* po = path + (size_t)b * T_LEN * T_LEN;
        po[ix * T_LEN + iy] = 1.0f;
        while (ix > 0 || iy > 0) {
            uint4 tw = *reinterpret_cast<const uint4*>(
                &cho[((ix >> 2) * 32 + (iy >> 4)) * 4]);
            int tr = ix >> 2, tc = iy >> 4;
            while (true) {
                int sel = ix & 3;
                unsigned wv = (sel & 2) ? ((sel & 1) ? tw.w : tw.z)
                                        : ((sel & 1) ? tw.y : tw.x);
                int c = (wv >> ((iy & 15) * 2)) & 3;
                ix -= (c != 1);
                iy -= (c != 2);
                po[ix * T_LEN + iy] = 1.0f;
                if (!(ix > 0 || iy > 0)) break;
                if ((ix >> 2) != tr || (iy >> 4) != tc) break;
            }
        }
    }
}

// ---------------------------------------------------------------------------
extern "C" void kernel_launch(void* const* d_in, const int* in_sizes, int n_in,
                              void* d_out, int out_size, void* d_ws, size_t ws_size,
                              hipStream_t stream)
{
    (void)in_sizes; (void)n_in; (void)out_size; (void)ws_size;

    const float* vec   = (const float*)d_in[0];
    const float* music = (const float*)d_in[1];
    const int*   rlen  = (const int*)  d_in[2];
    const float* qw1 = (const float*)d_in[3];  const float* qb1 = (const float*)d_in[4];
    const float* qw2 = (const float*)d_in[5];  const float* qb2 = (const float*)d_in[6];
    const float* qw3 = (const float*)d_in[7];  const float* qb3 = (const float*)d_in[8];
    const float* kw1 = (const float*)d_in[9];  const float* kb1 = (const float*)d_in[10];
    const float* kw2 = (const float*)d_in[11]; const float* kb2 = (const float*)d_in[12];
    const float* kw3 = (const float*)d_in[13]; const float* kb3 = (const float*)d_in[14];

    float* out = (float*)d_out;
    const size_t mat_elems = (size_t)BATCH * T_LEN * T_LEN;
    float* path_out = out;
    float* dist_out = out + mat_elems;

    // ws layout: [0, 8MB): conv buffers qA/qB/kA/kB, later reused as distT.
    //            [8MB, 8MB+8): min/max atomics.
    char* ws = (char*)d_ws;
    const size_t bufB = (size_t)BATCH * HID * T_LEN * sizeof(float);  // 2 MiB
    float* qA = (float*)(ws + 0 * bufB);
    float* qB = (float*)(ws + 1 * bufB);
    float* kA = (float*)(ws + 2 * bufB);
    float* kB = (float*)(ws + 3 * bufB);
    float* distT = (float*)ws;                      // overlaps qA..kB (dead then)
    unsigned* mm = (unsigned*)(ws + 4 * bufB);

    hipMemsetAsync(path_out, 0, mat_elems * sizeof(float), stream);
    hipMemsetAsync(mm, 0xFF, 4, stream);
    hipMemsetAsync(mm + 1, 0x00, 4, stream);

    dim3 cb(512);
    conv_block_kernel<<<dim3(8, 8, 8), cb, 0, stream>>>(vec, qw1, qb1, qA, 126, 126);
    conv_block_kernel<<<dim3(8, 8, 8), cb, 0, stream>>>(qA,  qw2, qb2, qB, 126, 128);
    conv_block_kernel<<<dim3(8, 8, 8), cb, 0, stream>>>(qB,  qw3, qb3, qA, 128, 128);
    conv_block_kernel<<<dim3(8, 5, 8), cb, 0, stream>>>(music, kw1, kb1, kA, 80, 80);
    conv_block_kernel<<<dim3(8, 8, 8), cb, 0, stream>>>(kA,   kw2, kb2, kB, 80, 128);
    conv_block_kernel<<<dim3(8, 8, 8), cb, 0, stream>>>(kB,   kw3, kb3, kA, 128, 128);

    dist_kernel<<<dim3(16, 16, 8), dim3(256), 0, stream>>>(qA, kA, dist_out, mm);

    norm_transpose_kernel<<<dim3(16, 16, 8), dim3(256), 0, stream>>>(dist_out, distT, mm);

    dtw_wave_kernel<<<dim3(BATCH), dim3(64), 0, stream>>>(distT, rlen, path_out);
}